// Round 4
// baseline (7620.752 us; speedup 1.0000x reference)
//
#include <hip/hip_runtime.h>

// MiniRocket on MI355X — round 3 (resubmit round 4; never executed due to
// GPU acquisition timeout).
// N=256, L=1024, 84 kernels (C(9,3)), 9996 features, 25 dilations.
//
// Pipeline:
//   1. mr_transpose: x (256,1024) -> zero-padded xTp (2048,256), data rows 512..1535
//      (pad replicates the reference's jnp.pad zeros exactly; taps never bounds-check)
//   2. mr_main: 256-thread blocks, 4 independent waves; wave = (dil, 12-kernel group,
//      4-bias split, 64-sample chunk, 1/16 t-slice); lane = sample; per-lane register
//      counters -> atomicAdd into u32 outT(9996,256)
//   3. mr_finalize: scale by 1/T (padded vs cropped) + transpose -> out(256,9996)
//
// ws layout: [0, 2MB) xTp ; [2MB, 2MB+9.77MB) outT. Total ~12.3 MB.

namespace {

constexpr int LSER = 1024;
constexpr int NS   = 256;
constexpr int NFEAT = 9996;
constexpr int NDIL = 25;
constexpr int GK   = 12;             // kernels per work item (84/12 = 7 groups)
constexpr int TCH  = 64;             // t per work item (16 slices)
constexpr int NWORK = 14336;         // total work items (waves)
constexpr int PADROWS = 2048;        // padded rows: data at [512, 1536)
constexpr int ROW0 = 512;

__constant__ int c_DIL[NDIL] = {1,2,3,4,5,6,7,8,10,12,14,16,19,22,26,31,36,42,50,58,68,79,93,109,127};
__constant__ int c_F[NDIL]   = {19,12,4,8,4,4,4,4,4,4,4,4,4,4,4,4,4,3,3,3,3,3,3,3,3};
__constant__ int c_FOFF[NDIL + 1] = {
    0,1596,2604,2940,3612,3948,4284,4620,4956,5292,5628,5964,6300,6636,6972,
    7308,7644,7980,8232,8484,8736,8988,9240,9492,9744,9996};
__constant__ int c_ISTART[NDIL + 1] = {
    0,2240,3584,4032,4928,5376,5824,6272,6720,7168,7616,8064,8512,8960,9408,
    9856,10304,10752,11200,11648,12096,12544,12992,13440,13888,14336};

constexpr int CIDX[84][3] = {
    {0,1,2},{0,1,3},{0,1,4},{0,1,5},{0,1,6},{0,1,7},{0,1,8},
    {0,2,3},{0,2,4},{0,2,5},{0,2,6},{0,2,7},{0,2,8},
    {0,3,4},{0,3,5},{0,3,6},{0,3,7},{0,3,8},
    {0,4,5},{0,4,6},{0,4,7},{0,4,8},
    {0,5,6},{0,5,7},{0,5,8},
    {0,6,7},{0,6,8},
    {0,7,8},
    {1,2,3},{1,2,4},{1,2,5},{1,2,6},{1,2,7},{1,2,8},
    {1,3,4},{1,3,5},{1,3,6},{1,3,7},{1,3,8},
    {1,4,5},{1,4,6},{1,4,7},{1,4,8},
    {1,5,6},{1,5,7},{1,5,8},
    {1,6,7},{1,6,8},
    {1,7,8},
    {2,3,4},{2,3,5},{2,3,6},{2,3,7},{2,3,8},
    {2,4,5},{2,4,6},{2,4,7},{2,4,8},
    {2,5,6},{2,5,7},{2,5,8},
    {2,6,7},{2,6,8},
    {2,7,8},
    {3,4,5},{3,4,6},{3,4,7},{3,4,8},
    {3,5,6},{3,5,7},{3,5,8},
    {3,6,7},{3,6,8},
    {3,7,8},
    {4,5,6},{4,5,7},{4,5,8},
    {4,6,7},{4,6,8},
    {4,7,8},
    {5,6,7},{5,6,8},
    {5,7,8},
    {6,7,8}};

__device__ __forceinline__ int imin(int a, int b) { return a < b ? a : b; }
__device__ __forceinline__ int imax(int a, int b) { return a > b ? a : b; }

// PSEL < 0: all kernels. PSEL 0/1: kernels with (K0+KK)&1 == PSEL (padded parity).
template <int K0, int FS, int PSEL, int KK>
__device__ __forceinline__ void do_kernels(const float (&s)[9], float sum,
                                           const float (&bv)[GK][FS],
                                           unsigned (&cnt)[GK][FS]) {
  if constexpr (KK < GK) {
    if constexpr (PSEL < 0 || (((K0 + KK) & 1) == PSEL)) {
      constexpr int ia = CIDX[K0 + KK][0];
      constexpr int ib = CIDX[K0 + KK][1];
      constexpr int ic = CIDX[K0 + KK][2];
      // reference op order: 3.0*(s[a]+s[b]+s[c]) - sum, no FMA contraction.
      // (s[ia]+s[ib]) written so the compiler CSEs shared pairs across kernels.
      float s3 = (s[ia] + s[ib]) + s[ic];
      float cv = __fsub_rn(__fmul_rn(3.0f, s3), sum);
#pragma unroll
      for (int j = 0; j < FS; ++j) cnt[KK][j] += (cv > bv[KK][j]) ? 1u : 0u;
    }
    do_kernels<K0, FS, PSEL, KK + 1>(s, sum, bv, cnt);
  }
}

template <int K0, int FS, int KK>
__device__ __forceinline__ void init_k(const float* __restrict__ biases,
                                       int colbase, int FTOT, int jb,
                                       float (&bv)[GK][FS], unsigned (&cnt)[GK][FS]) {
  if constexpr (KK < GK) {
    const int cb = colbase + (K0 + KK) * FTOT + jb;
#pragma unroll
    for (int j = 0; j < FS; ++j) {
      bv[KK][j] = biases[cb + j];  // uniform -> SGPR
      cnt[KK][j] = 0u;
    }
    init_k<K0, FS, KK + 1>(biases, colbase, FTOT, jb, bv, cnt);
  }
}

template <int K0, int FS, int KK>
__device__ __forceinline__ void write_k(unsigned* __restrict__ outT, int colbase,
                                        int FTOT, int jb, int n,
                                        const unsigned (&cnt)[GK][FS]) {
  if constexpr (KK < GK) {
    const int cb = colbase + (K0 + KK) * FTOT + jb;
#pragma unroll
    for (int j = 0; j < FS; ++j) {
      atomicAdd(&outT[(cb + j) * NS + n], cnt[KK][j]);  // coalesced per wave
    }
    write_k<K0, FS, KK + 1>(outT, colbase, FTOT, jb, n, cnt);
  }
}

// One t-range segment. Taps are unconditional loads from the padded array:
// bp[j] is a wave-uniform base pointer (saddr), voff a per-lane 32-bit offset.
template <int K0, int FS, int PSEL>
__device__ __forceinline__ void run_seg(int tlo, int thi, int n,
                                        const float* const (&bp)[9],
                                        const float (&bv)[GK][FS],
                                        unsigned (&cnt)[GK][FS]) {
  int voff = tlo * NS + n;
  for (int t = tlo; t < thi; ++t, voff += NS) {
    float s[9];
#pragma unroll
    for (int j = 0; j < 9; ++j) s[j] = bp[j][voff];
    // sequential left-fold, matching reference reduce order (pad zeros included)
    float sum = s[0];
#pragma unroll
    for (int j = 1; j < 9; ++j) sum += s[j];
    do_kernels<K0, FS, PSEL, 0>(s, sum, bv, cnt);
  }
}

template <int K0, int FS>
__device__ __forceinline__ void body(const float* __restrict__ xTp,
                                     const float* __restrict__ biases,
                                     unsigned* __restrict__ outT, int d, int par,
                                     int FTOT, int jb, int colbase, int nc, int ts) {
  const int lane = (int)(threadIdx.x & 63);
  const int n = (nc << 6) + lane;

  // 9 wave-uniform tap bases: row (ROW0 - 4d + j*d) onward; lane offset added via voff.
  const float* bp[9];
#pragma unroll
  for (int j = 0; j < 9; ++j) bp[j] = xTp + (ROW0 - 4 * d + j * d) * NS;

  float bv[GK][FS];
  unsigned cnt[GK][FS];
  init_k<K0, FS, 0>(biases, colbase, FTOT, jb, bv, cnt);

  const int p = 4 * d;
  const int t0 = ts * TCH, t1 = t0 + TCH;
  // [0,p) and [L-p,L): padded-parity kernels only. [p,L-p): all kernels.
  const int aHi = imin(t1, p);
  const int bLo = imax(t0, p), bHi = imin(t1, LSER - p);
  const int cLo = imax(t0, LSER - p);

  if (par == 0) {
    run_seg<K0, FS, 0>(t0, aHi, n, bp, bv, cnt);
  } else {
    run_seg<K0, FS, 1>(t0, aHi, n, bp, bv, cnt);
  }
  run_seg<K0, FS, -1>(bLo, bHi, n, bp, bv, cnt);
  if (par == 0) {
    run_seg<K0, FS, 0>(cLo, t1, n, bp, bv, cnt);
  } else {
    run_seg<K0, FS, 1>(cLo, t1, n, bp, bv, cnt);
  }

  write_k<K0, FS, 0>(outT, colbase, FTOT, jb, n, cnt);
}

}  // namespace

// ---------------------------------------------------------------------------

__global__ __launch_bounds__(256) void mr_transpose(const float* __restrict__ x,
                                                    float* __restrict__ xTp) {
  __shared__ float tile[32][33];
  const int t0 = blockIdx.x << 5;
  const int n0 = blockIdx.y << 5;
  const int tx = threadIdx.x & 31, ty = threadIdx.x >> 5;  // 32 x 8
#pragma unroll
  for (int i = 0; i < 32; i += 8)
    tile[ty + i][tx] = x[(n0 + ty + i) * LSER + t0 + tx];
  __syncthreads();
#pragma unroll
  for (int i = 0; i < 32; i += 8)
    xTp[(ROW0 + t0 + ty + i) * NS + n0 + tx] = tile[tx][ty + i];
}

__global__ __launch_bounds__(256) void mr_main(const float* __restrict__ xTp,
                                               const float* __restrict__ biases,
                                               unsigned* __restrict__ outT) {
  const int w = (int)blockIdx.x * 4 + (int)(threadIdx.x >> 6);  // work item = wave
  int di = 0;
#pragma unroll 1
  while (di < NDIL - 1 && w >= c_ISTART[di + 1]) ++di;
  const int rel = w - c_ISTART[di];
  const int split = rel / 448;          // 4-wide bias split
  const int r2 = rel - split * 448;
  const int g = r2 >> 6;                // kernel group 0..6
  const int r3 = r2 & 63;
  const int nc = r3 >> 4;               // sample chunk 0..3
  const int ts = r3 & 15;               // t-slice 0..15
  const int d = c_DIL[di];
  const int FTOT = c_F[di];
  const int colbase = c_FOFF[di];
  const int par = di & 1;
  const int jb = split << 2;
  const int FS = imin(4, FTOT - jb);

  if (FS == 4) {
    switch (g) {
      case 0: body<0, 4>(xTp, biases, outT, d, par, FTOT, jb, colbase, nc, ts); break;
      case 1: body<12, 4>(xTp, biases, outT, d, par, FTOT, jb, colbase, nc, ts); break;
      case 2: body<24, 4>(xTp, biases, outT, d, par, FTOT, jb, colbase, nc, ts); break;
      case 3: body<36, 4>(xTp, biases, outT, d, par, FTOT, jb, colbase, nc, ts); break;
      case 4: body<48, 4>(xTp, biases, outT, d, par, FTOT, jb, colbase, nc, ts); break;
      case 5: body<60, 4>(xTp, biases, outT, d, par, FTOT, jb, colbase, nc, ts); break;
      default: body<72, 4>(xTp, biases, outT, d, par, FTOT, jb, colbase, nc, ts); break;
    }
  } else {  // FS == 3
    switch (g) {
      case 0: body<0, 3>(xTp, biases, outT, d, par, FTOT, jb, colbase, nc, ts); break;
      case 1: body<12, 3>(xTp, biases, outT, d, par, FTOT, jb, colbase, nc, ts); break;
      case 2: body<24, 3>(xTp, biases, outT, d, par, FTOT, jb, colbase, nc, ts); break;
      case 3: body<36, 3>(xTp, biases, outT, d, par, FTOT, jb, colbase, nc, ts); break;
      case 4: body<48, 3>(xTp, biases, outT, d, par, FTOT, jb, colbase, nc, ts); break;
      case 5: body<60, 3>(xTp, biases, outT, d, par, FTOT, jb, colbase, nc, ts); break;
      default: body<72, 3>(xTp, biases, outT, d, par, FTOT, jb, colbase, nc, ts); break;
    }
  }
}

__global__ __launch_bounds__(256) void mr_finalize(const unsigned* __restrict__ outT,
                                                   float* __restrict__ out) {
  __shared__ unsigned tile[64][65];
  __shared__ float sscale[64];
  const int tb = (int)blockIdx.x;  // 628 = 157 col-tiles x 4 n-tiles
  const int ct = tb % 157, nt = tb / 157;
  const int c0 = ct << 6, n0 = nt << 6;
  const int tid = (int)threadIdx.x;

  if (tid < 64) {
    const int col = c0 + tid;
    float sc = 0.0f;
    if (col < NFEAT) {
      int di = 0;
      while (di < NDIL - 1 && col >= c_FOFF[di + 1]) ++di;
      const int rel = col - c_FOFF[di];
      const int f = c_F[di];
      const int k = rel / f;
      const int d = c_DIL[di];
      const bool padded = (((di + k) & 1) == 0);
      const int T = padded ? LSER : (LSER - 8 * d);
      sc = 1.0f / (float)T;
    }
    sscale[tid] = sc;
  }
#pragma unroll
  for (int i = 0; i < 16; ++i) {
    const int lin = tid + (i << 8);
    const int dc = lin >> 6, dn = lin & 63;
    const int col = c0 + dc;
    tile[dc][dn] = (col < NFEAT) ? outT[col * NS + n0 + dn] : 0u;
  }
  __syncthreads();
#pragma unroll
  for (int i = 0; i < 16; ++i) {
    const int lin = tid + (i << 8);
    const int dn = lin >> 6, dc = lin & 63;
    const int col = c0 + dc;
    if (col < NFEAT)
      out[(n0 + dn) * NFEAT + col] = (float)tile[dc][dn] * sscale[dc];
  }
}

extern "C" void kernel_launch(void* const* d_in, const int* in_sizes, int n_in,
                              void* d_out, int out_size, void* d_ws, size_t ws_size,
                              hipStream_t stream) {
  (void)in_sizes; (void)n_in; (void)out_size; (void)ws_size;
  const float* x = (const float*)d_in[0];        // (256, 1, 1024) f32
  const float* biases = (const float*)d_in[1];   // (9996,) f32
  float* out = (float*)d_out;                    // (256, 9996) f32

  float* xTp = (float*)d_ws;                                   // 2 MiB (2048x256 f32)
  unsigned* outT = (unsigned*)((char*)d_ws + (size_t)(PADROWS * NS * 4));

  // zero pad rows + counters in one memset (regions are contiguous)
  hipMemsetAsync(d_ws, 0,
                 (size_t)PADROWS * NS * 4 + (size_t)NFEAT * NS * sizeof(unsigned),
                 stream);
  hipLaunchKernelGGL(mr_transpose, dim3(32, 8), dim3(256), 0, stream, x, xTp);
  hipLaunchKernelGGL(mr_main, dim3(NWORK / 4), dim3(256), 0, stream, xTp, biases, outT);
  hipLaunchKernelGGL(mr_finalize, dim3(628), dim3(256), 0, stream, outT, out);
}

// Round 5
// 6408.631 us; speedup vs baseline: 1.1891x; 1.1891x over previous
//
#include <hip/hip_runtime.h>

// MiniRocket on MI355X — round 5.
// Round-4 lesson: work-item selectors MUST be blockIdx-only. Making them
// threadIdx-dependent (w = bid*4 + tid>>6) destroyed provable wave-uniformity:
// biases fell out of SGPRs into VGPRs, VGPR 96->256, spill -> 12 GB scratch
// traffic, 23x regression. This round: 256-thread blocks where all 4 waves
// share (dil, kernel group, bias split, t-slice) from blockIdx; waves differ
// only in sample chunk (nc = tid>>6, so n = threadIdx.x).
//
// Pipeline:
//   1. mr_transpose: x (256,1024) -> zero-padded xTp (2048,256), data rows 512..1535
//   2. mr_main: 3584 blocks x 256 thr; per-lane register counters ->
//      atomicAdd into u32 outT(9996,256)
//   3. mr_finalize: scale by 1/T (padded vs cropped) + transpose -> out(256,9996)
//
// ws layout: [0, 2MB) xTp ; [2MB, +9.77MB) outT. Total ~12.3 MB.

namespace {

constexpr int LSER = 1024;
constexpr int NS   = 256;
constexpr int NFEAT = 9996;
constexpr int NDIL = 25;
constexpr int GK   = 12;             // kernels per work item (84/12 = 7 groups)
constexpr int TCH  = 64;             // t per work item (16 slices)
constexpr int NBLK = 3584;           // blocks: sum_di ceil(F/4)*7*16
constexpr int PADROWS = 2048;        // padded rows: data at [512, 1536)
constexpr int ROW0 = 512;

__constant__ int c_DIL[NDIL] = {1,2,3,4,5,6,7,8,10,12,14,16,19,22,26,31,36,42,50,58,68,79,93,109,127};
__constant__ int c_F[NDIL]   = {19,12,4,8,4,4,4,4,4,4,4,4,4,4,4,4,4,3,3,3,3,3,3,3,3};
__constant__ int c_FOFF[NDIL + 1] = {
    0,1596,2604,2940,3612,3948,4284,4620,4956,5292,5628,5964,6300,6636,6972,
    7308,7644,7980,8232,8484,8736,8988,9240,9492,9744,9996};
// block-id start per dilation: ceil(F/4)*7*16 blocks each
__constant__ int c_BSTART[NDIL + 1] = {
    0,560,896,1008,1232,1344,1456,1568,1680,1792,1904,2016,2128,2240,2352,
    2464,2576,2688,2800,2912,3024,3136,3248,3360,3472,3584};

constexpr int CIDX[84][3] = {
    {0,1,2},{0,1,3},{0,1,4},{0,1,5},{0,1,6},{0,1,7},{0,1,8},
    {0,2,3},{0,2,4},{0,2,5},{0,2,6},{0,2,7},{0,2,8},
    {0,3,4},{0,3,5},{0,3,6},{0,3,7},{0,3,8},
    {0,4,5},{0,4,6},{0,4,7},{0,4,8},
    {0,5,6},{0,5,7},{0,5,8},
    {0,6,7},{0,6,8},
    {0,7,8},
    {1,2,3},{1,2,4},{1,2,5},{1,2,6},{1,2,7},{1,2,8},
    {1,3,4},{1,3,5},{1,3,6},{1,3,7},{1,3,8},
    {1,4,5},{1,4,6},{1,4,7},{1,4,8},
    {1,5,6},{1,5,7},{1,5,8},
    {1,6,7},{1,6,8},
    {1,7,8},
    {2,3,4},{2,3,5},{2,3,6},{2,3,7},{2,3,8},
    {2,4,5},{2,4,6},{2,4,7},{2,4,8},
    {2,5,6},{2,5,7},{2,5,8},
    {2,6,7},{2,6,8},
    {2,7,8},
    {3,4,5},{3,4,6},{3,4,7},{3,4,8},
    {3,5,6},{3,5,7},{3,5,8},
    {3,6,7},{3,6,8},
    {3,7,8},
    {4,5,6},{4,5,7},{4,5,8},
    {4,6,7},{4,6,8},
    {4,7,8},
    {5,6,7},{5,6,8},
    {5,7,8},
    {6,7,8}};

__device__ __forceinline__ int imin(int a, int b) { return a < b ? a : b; }
__device__ __forceinline__ int imax(int a, int b) { return a > b ? a : b; }

// PSEL < 0: all kernels. PSEL 0/1: kernels with (K0+KK)&1 == PSEL (padded parity).
template <int K0, int FS, int PSEL, int KK>
__device__ __forceinline__ void do_kernels(const float (&s)[9], float sum,
                                           const float (&bv)[GK][FS],
                                           unsigned (&cnt)[GK][FS]) {
  if constexpr (KK < GK) {
    if constexpr (PSEL < 0 || (((K0 + KK) & 1) == PSEL)) {
      constexpr int ia = CIDX[K0 + KK][0];
      constexpr int ib = CIDX[K0 + KK][1];
      constexpr int ic = CIDX[K0 + KK][2];
      // reference op order: 3.0*(s[a]+s[b]+s[c]) - sum, no FMA contraction.
      float s3 = (s[ia] + s[ib]) + s[ic];
      float cv = __fsub_rn(__fmul_rn(3.0f, s3), sum);
#pragma unroll
      for (int j = 0; j < FS; ++j) cnt[KK][j] += (cv > bv[KK][j]) ? 1u : 0u;
    }
    do_kernels<K0, FS, PSEL, KK + 1>(s, sum, bv, cnt);
  }
}

template <int K0, int FS, int KK>
__device__ __forceinline__ void init_k(const float* __restrict__ biases,
                                       int colbase, int FTOT, int jb,
                                       float (&bv)[GK][FS], unsigned (&cnt)[GK][FS]) {
  if constexpr (KK < GK) {
    const int cb = colbase + (K0 + KK) * FTOT + jb;  // block-uniform -> s_load
#pragma unroll
    for (int j = 0; j < FS; ++j) {
      bv[KK][j] = biases[cb + j];
      cnt[KK][j] = 0u;
    }
    init_k<K0, FS, KK + 1>(biases, colbase, FTOT, jb, bv, cnt);
  }
}

template <int K0, int FS, int KK>
__device__ __forceinline__ void write_k(unsigned* __restrict__ outT, int colbase,
                                        int FTOT, int jb, int n,
                                        const unsigned (&cnt)[GK][FS]) {
  if constexpr (KK < GK) {
    const int cb = colbase + (K0 + KK) * FTOT + jb;
#pragma unroll
    for (int j = 0; j < FS; ++j) {
      atomicAdd(&outT[(cb + j) * NS + n], cnt[KK][j]);  // coalesced per wave
    }
    write_k<K0, FS, KK + 1>(outT, colbase, FTOT, jb, n, cnt);
  }
}

// One t-range segment. Taps are unconditional loads from the padded array:
// bp[j] is a block-uniform base pointer (saddr), voff a per-lane 32-bit offset.
template <int K0, int FS, int PSEL>
__device__ __forceinline__ void run_seg(int tlo, int thi, int n,
                                        const float* const (&bp)[9],
                                        const float (&bv)[GK][FS],
                                        unsigned (&cnt)[GK][FS]) {
  int voff = tlo * NS + n;
  for (int t = tlo; t < thi; ++t, voff += NS) {
    float s[9];
#pragma unroll
    for (int j = 0; j < 9; ++j) s[j] = bp[j][voff];
    // sequential left-fold, matching reference reduce order (pad zeros included)
    float sum = s[0];
#pragma unroll
    for (int j = 1; j < 9; ++j) sum += s[j];
    do_kernels<K0, FS, PSEL, 0>(s, sum, bv, cnt);
  }
}

template <int K0, int FS>
__device__ __forceinline__ void body(const float* __restrict__ xTp,
                                     const float* __restrict__ biases,
                                     unsigned* __restrict__ outT, int d, int par,
                                     int FTOT, int jb, int colbase, int ts) {
  const int n = (int)threadIdx.x;  // nc = tid>>6 folded in: n = nc*64 + lane

  // 9 block-uniform tap bases; lane offset added via voff.
  const float* bp[9];
#pragma unroll
  for (int j = 0; j < 9; ++j) bp[j] = xTp + (ROW0 - 4 * d + j * d) * NS;

  float bv[GK][FS];
  unsigned cnt[GK][FS];
  init_k<K0, FS, 0>(biases, colbase, FTOT, jb, bv, cnt);

  const int p = 4 * d;
  const int t0 = ts * TCH, t1 = t0 + TCH;
  // [0,p) and [L-p,L): padded-parity kernels only. [p,L-p): all kernels.
  const int aHi = imin(t1, p);
  const int bLo = imax(t0, p), bHi = imin(t1, LSER - p);
  const int cLo = imax(t0, LSER - p);

  if (par == 0) {
    run_seg<K0, FS, 0>(t0, aHi, n, bp, bv, cnt);
  } else {
    run_seg<K0, FS, 1>(t0, aHi, n, bp, bv, cnt);
  }
  run_seg<K0, FS, -1>(bLo, bHi, n, bp, bv, cnt);
  if (par == 0) {
    run_seg<K0, FS, 0>(cLo, t1, n, bp, bv, cnt);
  } else {
    run_seg<K0, FS, 1>(cLo, t1, n, bp, bv, cnt);
  }

  write_k<K0, FS, 0>(outT, colbase, FTOT, jb, n, cnt);
}

}  // namespace

// ---------------------------------------------------------------------------

__global__ __launch_bounds__(256) void mr_transpose(const float* __restrict__ x,
                                                    float* __restrict__ xTp) {
  __shared__ float tile[32][33];
  const int t0 = blockIdx.x << 5;
  const int n0 = blockIdx.y << 5;
  const int tx = threadIdx.x & 31, ty = threadIdx.x >> 5;  // 32 x 8
#pragma unroll
  for (int i = 0; i < 32; i += 8)
    tile[ty + i][tx] = x[(n0 + ty + i) * LSER + t0 + tx];
  __syncthreads();
#pragma unroll
  for (int i = 0; i < 32; i += 8)
    xTp[(ROW0 + t0 + ty + i) * NS + n0 + tx] = tile[tx][ty + i];
}

__global__ __launch_bounds__(256) void mr_main(const float* __restrict__ xTp,
                                               const float* __restrict__ biases,
                                               unsigned* __restrict__ outT) {
  const int bid = (int)blockIdx.x;  // ALL selectors blockIdx-only (wave-uniform)
  int di = 0;
#pragma unroll 1
  while (di < NDIL - 1 && bid >= c_BSTART[di + 1]) ++di;
  const int rel = bid - c_BSTART[di];
  const int split = rel / 112;          // 4-wide bias split (7 groups x 16 ts = 112)
  const int r2 = rel - split * 112;
  const int g = r2 >> 4;                // kernel group 0..6
  const int ts = r2 & 15;               // t-slice 0..15
  const int d = c_DIL[di];
  const int FTOT = c_F[di];
  const int colbase = c_FOFF[di];
  const int par = di & 1;
  const int jb = split << 2;
  const int FS = imin(4, FTOT - jb);

  if (FS == 4) {
    switch (g) {
      case 0: body<0, 4>(xTp, biases, outT, d, par, FTOT, jb, colbase, ts); break;
      case 1: body<12, 4>(xTp, biases, outT, d, par, FTOT, jb, colbase, ts); break;
      case 2: body<24, 4>(xTp, biases, outT, d, par, FTOT, jb, colbase, ts); break;
      case 3: body<36, 4>(xTp, biases, outT, d, par, FTOT, jb, colbase, ts); break;
      case 4: body<48, 4>(xTp, biases, outT, d, par, FTOT, jb, colbase, ts); break;
      case 5: body<60, 4>(xTp, biases, outT, d, par, FTOT, jb, colbase, ts); break;
      default: body<72, 4>(xTp, biases, outT, d, par, FTOT, jb, colbase, ts); break;
    }
  } else {  // FS == 3
    switch (g) {
      case 0: body<0, 3>(xTp, biases, outT, d, par, FTOT, jb, colbase, ts); break;
      case 1: body<12, 3>(xTp, biases, outT, d, par, FTOT, jb, colbase, ts); break;
      case 2: body<24, 3>(xTp, biases, outT, d, par, FTOT, jb, colbase, ts); break;
      case 3: body<36, 3>(xTp, biases, outT, d, par, FTOT, jb, colbase, ts); break;
      case 4: body<48, 3>(xTp, biases, outT, d, par, FTOT, jb, colbase, ts); break;
      case 5: body<60, 3>(xTp, biases, outT, d, par, FTOT, jb, colbase, ts); break;
      default: body<72, 3>(xTp, biases, outT, d, par, FTOT, jb, colbase, ts); break;
    }
  }
}

__global__ __launch_bounds__(256) void mr_finalize(const unsigned* __restrict__ outT,
                                                   float* __restrict__ out) {
  __shared__ unsigned tile[64][65];
  __shared__ float sscale[64];
  const int tb = (int)blockIdx.x;  // 628 = 157 col-tiles x 4 n-tiles
  const int ct = tb % 157, nt = tb / 157;
  const int c0 = ct << 6, n0 = nt << 6;
  const int tid = (int)threadIdx.x;

  if (tid < 64) {
    const int col = c0 + tid;
    float sc = 0.0f;
    if (col < NFEAT) {
      int di = 0;
      while (di < NDIL - 1 && col >= c_FOFF[di + 1]) ++di;
      const int rel = col - c_FOFF[di];
      const int f = c_F[di];
      const int k = rel / f;
      const int d = c_DIL[di];
      const bool padded = (((di + k) & 1) == 0);
      const int T = padded ? LSER : (LSER - 8 * d);
      sc = 1.0f / (float)T;
    }
    sscale[tid] = sc;
  }
#pragma unroll
  for (int i = 0; i < 16; ++i) {
    const int lin = tid + (i << 8);
    const int dc = lin >> 6, dn = lin & 63;
    const int col = c0 + dc;
    tile[dc][dn] = (col < NFEAT) ? outT[col * NS + n0 + dn] : 0u;
  }
  __syncthreads();
#pragma unroll
  for (int i = 0; i < 16; ++i) {
    const int lin = tid + (i << 8);
    const int dn = lin >> 6, dc = lin & 63;
    const int col = c0 + dc;
    if (col < NFEAT)
      out[(n0 + dn) * NFEAT + col] = (float)tile[dc][dn] * sscale[dc];
  }
}

extern "C" void kernel_launch(void* const* d_in, const int* in_sizes, int n_in,
                              void* d_out, int out_size, void* d_ws, size_t ws_size,
                              hipStream_t stream) {
  (void)in_sizes; (void)n_in; (void)out_size; (void)ws_size;
  const float* x = (const float*)d_in[0];        // (256, 1, 1024) f32
  const float* biases = (const float*)d_in[1];   // (9996,) f32
  float* out = (float*)d_out;                    // (256, 9996) f32

  float* xTp = (float*)d_ws;                                   // 2 MiB (2048x256 f32)
  unsigned* outT = (unsigned*)((char*)d_ws + (size_t)(PADROWS * NS * 4));

  // zero pad rows + counters in one memset (regions are contiguous)
  hipMemsetAsync(d_ws, 0,
                 (size_t)PADROWS * NS * 4 + (size_t)NFEAT * NS * sizeof(unsigned),
                 stream);
  hipLaunchKernelGGL(mr_transpose, dim3(32, 8), dim3(256), 0, stream, x, xTp);
  hipLaunchKernelGGL(mr_main, dim3(NBLK), dim3(256), 0, stream, xTp, biases, outT);
  hipLaunchKernelGGL(mr_finalize, dim3(628), dim3(256), 0, stream, outT, out);
}

// Round 6
// 1486.382 us; speedup vs baseline: 5.1270x; 4.3116x over previous
//
#include <hip/hip_runtime.h>

// MiniRocket on MI355X — round 6.
// Round-4/5 lesson: the 23x regression was register spill (VGPR 256, ~10 GB
// scratch traffic). Cause was NOT the selector uniformity (round 5 disproved);
// suspects are the bp[9] pointer array (SROA->scratch) and/or unroll-driven
// live-range blowup of the slim unconditional t-loop. This round removes both:
// round-2-proven single-base addressing xb[(t+j*d)*NS], #pragma unroll 1 on
// t-loops, and __launch_bounds__(256,4) (VGPR cap 128, scheduler targets it).
// Keeps: zero-padded xTp (no bounds checks), 256-thr blocks, blockIdx-only
// selectors.
//
// Pipeline:
//   1. mr_transpose: x (256,1024) -> zero-padded xTp (2048,256), data rows 512..1535
//   2. mr_main: 3584 blocks x 256 thr; wave-uniform (dil, kernel group, bias
//      split, t-slice) from blockIdx; lane+wave = sample n = threadIdx.x;
//      per-lane register counters -> atomicAdd into u32 outT(9996,256)
//   3. mr_finalize: scale by 1/T (padded vs cropped) + transpose -> out(256,9996)
//
// ws layout: [0, 2MB) xTp ; [2MB, +9.77MB) outT. Total ~12.3 MB.

namespace {

constexpr int LSER = 1024;
constexpr int NS   = 256;
constexpr int NFEAT = 9996;
constexpr int NDIL = 25;
constexpr int GK   = 12;             // kernels per work item (84/12 = 7 groups)
constexpr int TCH  = 64;             // t per work item (16 slices)
constexpr int NBLK = 3584;           // sum_di ceil(F/4)*7*16
constexpr int PADROWS = 2048;        // padded rows: data at [512, 1536)
constexpr int ROW0 = 512;

__constant__ int c_DIL[NDIL] = {1,2,3,4,5,6,7,8,10,12,14,16,19,22,26,31,36,42,50,58,68,79,93,109,127};
__constant__ int c_F[NDIL]   = {19,12,4,8,4,4,4,4,4,4,4,4,4,4,4,4,4,3,3,3,3,3,3,3,3};
__constant__ int c_FOFF[NDIL + 1] = {
    0,1596,2604,2940,3612,3948,4284,4620,4956,5292,5628,5964,6300,6636,6972,
    7308,7644,7980,8232,8484,8736,8988,9240,9492,9744,9996};
// block-id start per dilation: ceil(F/4)*7*16 blocks each
__constant__ int c_BSTART[NDIL + 1] = {
    0,560,896,1008,1232,1344,1456,1568,1680,1792,1904,2016,2128,2240,2352,
    2464,2576,2688,2800,2912,3024,3136,3248,3360,3472,3584};

constexpr int CIDX[84][3] = {
    {0,1,2},{0,1,3},{0,1,4},{0,1,5},{0,1,6},{0,1,7},{0,1,8},
    {0,2,3},{0,2,4},{0,2,5},{0,2,6},{0,2,7},{0,2,8},
    {0,3,4},{0,3,5},{0,3,6},{0,3,7},{0,3,8},
    {0,4,5},{0,4,6},{0,4,7},{0,4,8},
    {0,5,6},{0,5,7},{0,5,8},
    {0,6,7},{0,6,8},
    {0,7,8},
    {1,2,3},{1,2,4},{1,2,5},{1,2,6},{1,2,7},{1,2,8},
    {1,3,4},{1,3,5},{1,3,6},{1,3,7},{1,3,8},
    {1,4,5},{1,4,6},{1,4,7},{1,4,8},
    {1,5,6},{1,5,7},{1,5,8},
    {1,6,7},{1,6,8},
    {1,7,8},
    {2,3,4},{2,3,5},{2,3,6},{2,3,7},{2,3,8},
    {2,4,5},{2,4,6},{2,4,7},{2,4,8},
    {2,5,6},{2,5,7},{2,5,8},
    {2,6,7},{2,6,8},
    {2,7,8},
    {3,4,5},{3,4,6},{3,4,7},{3,4,8},
    {3,5,6},{3,5,7},{3,5,8},
    {3,6,7},{3,6,8},
    {3,7,8},
    {4,5,6},{4,5,7},{4,5,8},
    {4,6,7},{4,6,8},
    {4,7,8},
    {5,6,7},{5,6,8},
    {5,7,8},
    {6,7,8}};

__device__ __forceinline__ int imin(int a, int b) { return a < b ? a : b; }
__device__ __forceinline__ int imax(int a, int b) { return a > b ? a : b; }

// PSEL < 0: all kernels. PSEL 0/1: kernels with (K0+KK)&1 == PSEL (padded parity).
template <int K0, int FS, int PSEL, int KK>
__device__ __forceinline__ void do_kernels(const float (&s)[9], float sum,
                                           const float (&bv)[GK][FS],
                                           unsigned (&cnt)[GK][FS]) {
  if constexpr (KK < GK) {
    if constexpr (PSEL < 0 || (((K0 + KK) & 1) == PSEL)) {
      constexpr int ia = CIDX[K0 + KK][0];
      constexpr int ib = CIDX[K0 + KK][1];
      constexpr int ic = CIDX[K0 + KK][2];
      // reference op order: 3.0*(s[a]+s[b]+s[c]) - sum, no FMA contraction.
      float s3 = (s[ia] + s[ib]) + s[ic];
      float cv = __fsub_rn(__fmul_rn(3.0f, s3), sum);
#pragma unroll
      for (int j = 0; j < FS; ++j) cnt[KK][j] += (cv > bv[KK][j]) ? 1u : 0u;
    }
    do_kernels<K0, FS, PSEL, KK + 1>(s, sum, bv, cnt);
  }
}

template <int K0, int FS, int KK>
__device__ __forceinline__ void init_k(const float* __restrict__ biases,
                                       int colbase, int FTOT, int jb,
                                       float (&bv)[GK][FS], unsigned (&cnt)[GK][FS]) {
  if constexpr (KK < GK) {
    const int cb = colbase + (K0 + KK) * FTOT + jb;  // block-uniform -> s_load
#pragma unroll
    for (int j = 0; j < FS; ++j) {
      bv[KK][j] = biases[cb + j];
      cnt[KK][j] = 0u;
    }
    init_k<K0, FS, KK + 1>(biases, colbase, FTOT, jb, bv, cnt);
  }
}

template <int K0, int FS, int KK>
__device__ __forceinline__ void write_k(unsigned* __restrict__ outT, int colbase,
                                        int FTOT, int jb, int n,
                                        const unsigned (&cnt)[GK][FS]) {
  if constexpr (KK < GK) {
    const int cb = colbase + (K0 + KK) * FTOT + jb;
#pragma unroll
    for (int j = 0; j < FS; ++j) {
      atomicAdd(&outT[(cb + j) * NS + n], cnt[KK][j]);  // coalesced per wave
    }
    write_k<K0, FS, KK + 1>(outT, colbase, FTOT, jb, n, cnt);
  }
}

// One t-range segment. Taps are unconditional loads from the padded array,
// round-2-style addressing: single per-lane base xb, index (t + j*d)*NS.
// #pragma unroll 1: forbid unroll-driven live-range blowup (round-4/5 spill).
template <int K0, int FS, int PSEL>
__device__ __forceinline__ void run_seg(int tlo, int thi, int d,
                                        const float* __restrict__ xb,
                                        const float (&bv)[GK][FS],
                                        unsigned (&cnt)[GK][FS]) {
#pragma unroll 1
  for (int t = tlo; t < thi; ++t) {
    float s[9];
#pragma unroll
    for (int j = 0; j < 9; ++j) s[j] = xb[(t + j * d) * NS];
    // sequential left-fold, matching reference reduce order (pad zeros included)
    float sum = s[0];
#pragma unroll
    for (int j = 1; j < 9; ++j) sum += s[j];
    do_kernels<K0, FS, PSEL, 0>(s, sum, bv, cnt);
  }
}

template <int K0, int FS>
__device__ __forceinline__ void body(const float* __restrict__ xTp,
                                     const float* __restrict__ biases,
                                     unsigned* __restrict__ outT, int d, int par,
                                     int FTOT, int jb, int colbase, int ts) {
  const int n = (int)threadIdx.x;  // sample id (4 waves x 64 lanes)
  // per-lane base: row (ROW0 - 4d), sample n. Tap j at row offset (t + j*d).
  const float* xb = xTp + (ROW0 - 4 * d) * NS + n;

  float bv[GK][FS];
  unsigned cnt[GK][FS];
  init_k<K0, FS, 0>(biases, colbase, FTOT, jb, bv, cnt);

  const int p = 4 * d;
  const int t0 = ts * TCH, t1 = t0 + TCH;
  // [0,p) and [L-p,L): padded-parity kernels only. [p,L-p): all kernels.
  const int aHi = imin(t1, p);
  const int bLo = imax(t0, p), bHi = imin(t1, LSER - p);
  const int cLo = imax(t0, LSER - p);

  if (par == 0) {
    run_seg<K0, FS, 0>(t0, aHi, d, xb, bv, cnt);
  } else {
    run_seg<K0, FS, 1>(t0, aHi, d, xb, bv, cnt);
  }
  run_seg<K0, FS, -1>(bLo, bHi, d, xb, bv, cnt);
  if (par == 0) {
    run_seg<K0, FS, 0>(cLo, t1, d, xb, bv, cnt);
  } else {
    run_seg<K0, FS, 1>(cLo, t1, d, xb, bv, cnt);
  }

  write_k<K0, FS, 0>(outT, colbase, FTOT, jb, n, cnt);
}

}  // namespace

// ---------------------------------------------------------------------------

__global__ __launch_bounds__(256) void mr_transpose(const float* __restrict__ x,
                                                    float* __restrict__ xTp) {
  __shared__ float tile[32][33];
  const int t0 = blockIdx.x << 5;
  const int n0 = blockIdx.y << 5;
  const int tx = threadIdx.x & 31, ty = threadIdx.x >> 5;  // 32 x 8
#pragma unroll
  for (int i = 0; i < 32; i += 8)
    tile[ty + i][tx] = x[(n0 + ty + i) * LSER + t0 + tx];
  __syncthreads();
#pragma unroll
  for (int i = 0; i < 32; i += 8)
    xTp[(ROW0 + t0 + ty + i) * NS + n0 + tx] = tile[tx][ty + i];
}

__global__ __launch_bounds__(256, 4) void mr_main(const float* __restrict__ xTp,
                                                  const float* __restrict__ biases,
                                                  unsigned* __restrict__ outT) {
  const int bid = (int)blockIdx.x;  // ALL selectors blockIdx-only (wave-uniform)
  int di = 0;
#pragma unroll 1
  while (di < NDIL - 1 && bid >= c_BSTART[di + 1]) ++di;
  const int rel = bid - c_BSTART[di];
  const int split = rel / 112;          // 4-wide bias split (7 groups x 16 ts = 112)
  const int r2 = rel - split * 112;
  const int g = r2 >> 4;                // kernel group 0..6
  const int ts = r2 & 15;               // t-slice 0..15
  const int d = c_DIL[di];
  const int FTOT = c_F[di];
  const int colbase = c_FOFF[di];
  const int par = di & 1;
  const int jb = split << 2;
  const int FS = imin(4, FTOT - jb);

  if (FS == 4) {
    switch (g) {
      case 0: body<0, 4>(xTp, biases, outT, d, par, FTOT, jb, colbase, ts); break;
      case 1: body<12, 4>(xTp, biases, outT, d, par, FTOT, jb, colbase, ts); break;
      case 2: body<24, 4>(xTp, biases, outT, d, par, FTOT, jb, colbase, ts); break;
      case 3: body<36, 4>(xTp, biases, outT, d, par, FTOT, jb, colbase, ts); break;
      case 4: body<48, 4>(xTp, biases, outT, d, par, FTOT, jb, colbase, ts); break;
      case 5: body<60, 4>(xTp, biases, outT, d, par, FTOT, jb, colbase, ts); break;
      default: body<72, 4>(xTp, biases, outT, d, par, FTOT, jb, colbase, ts); break;
    }
  } else {  // FS == 3
    switch (g) {
      case 0: body<0, 3>(xTp, biases, outT, d, par, FTOT, jb, colbase, ts); break;
      case 1: body<12, 3>(xTp, biases, outT, d, par, FTOT, jb, colbase, ts); break;
      case 2: body<24, 3>(xTp, biases, outT, d, par, FTOT, jb, colbase, ts); break;
      case 3: body<36, 3>(xTp, biases, outT, d, par, FTOT, jb, colbase, ts); break;
      case 4: body<48, 3>(xTp, biases, outT, d, par, FTOT, jb, colbase, ts); break;
      case 5: body<60, 3>(xTp, biases, outT, d, par, FTOT, jb, colbase, ts); break;
      default: body<72, 3>(xTp, biases, outT, d, par, FTOT, jb, colbase, ts); break;
    }
  }
}

__global__ __launch_bounds__(256) void mr_finalize(const unsigned* __restrict__ outT,
                                                   float* __restrict__ out) {
  __shared__ unsigned tile[64][65];
  __shared__ float sscale[64];
  const int tb = (int)blockIdx.x;  // 628 = 157 col-tiles x 4 n-tiles
  const int ct = tb % 157, nt = tb / 157;
  const int c0 = ct << 6, n0 = nt << 6;
  const int tid = (int)threadIdx.x;

  if (tid < 64) {
    const int col = c0 + tid;
    float sc = 0.0f;
    if (col < NFEAT) {
      int di = 0;
      while (di < NDIL - 1 && col >= c_FOFF[di + 1]) ++di;
      const int rel = col - c_FOFF[di];
      const int f = c_F[di];
      const int k = rel / f;
      const int d = c_DIL[di];
      const bool padded = (((di + k) & 1) == 0);
      const int T = padded ? LSER : (LSER - 8 * d);
      sc = 1.0f / (float)T;
    }
    sscale[tid] = sc;
  }
#pragma unroll
  for (int i = 0; i < 16; ++i) {
    const int lin = tid + (i << 8);
    const int dc = lin >> 6, dn = lin & 63;
    const int col = c0 + dc;
    tile[dc][dn] = (col < NFEAT) ? outT[col * NS + n0 + dn] : 0u;
  }
  __syncthreads();
#pragma unroll
  for (int i = 0; i < 16; ++i) {
    const int lin = tid + (i << 8);
    const int dn = lin >> 6, dc = lin & 63;
    const int col = c0 + dc;
    if (col < NFEAT)
      out[(n0 + dn) * NFEAT + col] = (float)tile[dc][dn] * sscale[dc];
  }
}

extern "C" void kernel_launch(void* const* d_in, const int* in_sizes, int n_in,
                              void* d_out, int out_size, void* d_ws, size_t ws_size,
                              hipStream_t stream) {
  (void)in_sizes; (void)n_in; (void)out_size; (void)ws_size;
  const float* x = (const float*)d_in[0];        // (256, 1, 1024) f32
  const float* biases = (const float*)d_in[1];   // (9996,) f32
  float* out = (float*)d_out;                    // (256, 9996) f32

  float* xTp = (float*)d_ws;                                   // 2 MiB (2048x256 f32)
  unsigned* outT = (unsigned*)((char*)d_ws + (size_t)(PADROWS * NS * 4));

  // zero pad rows + counters in one memset (regions are contiguous)
  hipMemsetAsync(d_ws, 0,
                 (size_t)PADROWS * NS * 4 + (size_t)NFEAT * NS * sizeof(unsigned),
                 stream);
  hipLaunchKernelGGL(mr_transpose, dim3(32, 8), dim3(256), 0, stream, x, xTp);
  hipLaunchKernelGGL(mr_main, dim3(NBLK), dim3(256), 0, stream, xTp, biases, outT);
  hipLaunchKernelGGL(mr_finalize, dim3(628), dim3(256), 0, stream, outT, out);
}

// Round 9
// 357.527 us; speedup vs baseline: 21.3152x; 4.1574x over previous
//
#include <hip/hip_runtime.h>

// MiniRocket on MI355X — round 7 kernel (2nd resubmit, round 9; GPU timeouts,
// never ran). Spill history: r4/5 (live-state blowup via pointer array, VGPR
// 256 + 10 GB scratch), r6 (launch_bounds(256,4) pinned VGPR=64 < live set ->
// 6.3 GB scratch, HBM-bound at 54%). Fix: shrink live state below every
// heuristic's failure point: GK=6 (cnt 24 VGPR), no min-waves clamp.
// Keeps: zero-padded xTp (no bounds checks), 256-thr blocks, blockIdx-only
// selectors (wave-uniform -> biases in SGPRs), unroll-1 t-loop.
//
// Pipeline:
//   1. mr_transpose: x (256,1024) -> zero-padded xTp (2048,256), data rows 512..1535
//   2. mr_main: 7168 blocks x 256 thr; block = (dil, 6-kernel group, 4-bias
//      split, 1/16 t-slice); n = threadIdx.x; per-lane register counters ->
//      atomicAdd into u32 outT(9996,256)
//   3. mr_finalize: scale by 1/T (padded vs cropped) + transpose -> out(256,9996)
//
// ws layout: [0, 2MB) xTp ; [2MB, +9.77MB) outT. Total ~12.3 MB.

namespace {

constexpr int LSER = 1024;
constexpr int NS   = 256;
constexpr int NFEAT = 9996;
constexpr int NDIL = 25;
constexpr int GK   = 6;              // kernels per work item (84/6 = 14 groups)
constexpr int TCH  = 64;             // t per work item (16 slices)
constexpr int NBLK = 7168;           // sum_di ceil(F/4)*14*16
constexpr int PADROWS = 2048;        // padded rows: data at [512, 1536)
constexpr int ROW0 = 512;

__constant__ int c_DIL[NDIL] = {1,2,3,4,5,6,7,8,10,12,14,16,19,22,26,31,36,42,50,58,68,79,93,109,127};
__constant__ int c_F[NDIL]   = {19,12,4,8,4,4,4,4,4,4,4,4,4,4,4,4,4,3,3,3,3,3,3,3,3};
__constant__ int c_FOFF[NDIL + 1] = {
    0,1596,2604,2940,3612,3948,4284,4620,4956,5292,5628,5964,6300,6636,6972,
    7308,7644,7980,8232,8484,8736,8988,9240,9492,9744,9996};
// block-id start per dilation: ceil(F/4)*14*16 blocks each
__constant__ int c_BSTART[NDIL + 1] = {
    0,1120,1792,2016,2464,2688,2912,3136,3360,3584,3808,4032,4256,4480,4704,
    4928,5152,5376,5600,5824,6048,6272,6496,6720,6944,7168};

constexpr int CIDX[84][3] = {
    {0,1,2},{0,1,3},{0,1,4},{0,1,5},{0,1,6},{0,1,7},{0,1,8},
    {0,2,3},{0,2,4},{0,2,5},{0,2,6},{0,2,7},{0,2,8},
    {0,3,4},{0,3,5},{0,3,6},{0,3,7},{0,3,8},
    {0,4,5},{0,4,6},{0,4,7},{0,4,8},
    {0,5,6},{0,5,7},{0,5,8},
    {0,6,7},{0,6,8},
    {0,7,8},
    {1,2,3},{1,2,4},{1,2,5},{1,2,6},{1,2,7},{1,2,8},
    {1,3,4},{1,3,5},{1,3,6},{1,3,7},{1,3,8},
    {1,4,5},{1,4,6},{1,4,7},{1,4,8},
    {1,5,6},{1,5,7},{1,5,8},
    {1,6,7},{1,6,8},
    {1,7,8},
    {2,3,4},{2,3,5},{2,3,6},{2,3,7},{2,3,8},
    {2,4,5},{2,4,6},{2,4,7},{2,4,8},
    {2,5,6},{2,5,7},{2,5,8},
    {2,6,7},{2,6,8},
    {2,7,8},
    {3,4,5},{3,4,6},{3,4,7},{3,4,8},
    {3,5,6},{3,5,7},{3,5,8},
    {3,6,7},{3,6,8},
    {3,7,8},
    {4,5,6},{4,5,7},{4,5,8},
    {4,6,7},{4,6,8},
    {4,7,8},
    {5,6,7},{5,6,8},
    {5,7,8},
    {6,7,8}};

__device__ __forceinline__ int imin(int a, int b) { return a < b ? a : b; }
__device__ __forceinline__ int imax(int a, int b) { return a > b ? a : b; }

// PSEL < 0: all kernels. PSEL 0/1: kernels with (K0+KK)&1 == PSEL (padded parity).
template <int K0, int FS, int PSEL, int KK>
__device__ __forceinline__ void do_kernels(const float (&s)[9], float sum,
                                           const float (&bv)[GK][FS],
                                           unsigned (&cnt)[GK][FS]) {
  if constexpr (KK < GK) {
    if constexpr (PSEL < 0 || (((K0 + KK) & 1) == PSEL)) {
      constexpr int ia = CIDX[K0 + KK][0];
      constexpr int ib = CIDX[K0 + KK][1];
      constexpr int ic = CIDX[K0 + KK][2];
      // reference op order: 3.0*(s[a]+s[b]+s[c]) - sum, no FMA contraction.
      float s3 = (s[ia] + s[ib]) + s[ic];
      float cv = __fsub_rn(__fmul_rn(3.0f, s3), sum);
#pragma unroll
      for (int j = 0; j < FS; ++j) cnt[KK][j] += (cv > bv[KK][j]) ? 1u : 0u;
    }
    do_kernels<K0, FS, PSEL, KK + 1>(s, sum, bv, cnt);
  }
}

template <int K0, int FS, int KK>
__device__ __forceinline__ void init_k(const float* __restrict__ biases,
                                       int colbase, int FTOT, int jb,
                                       float (&bv)[GK][FS], unsigned (&cnt)[GK][FS]) {
  if constexpr (KK < GK) {
    const int cb = colbase + (K0 + KK) * FTOT + jb;  // block-uniform -> s_load
#pragma unroll
    for (int j = 0; j < FS; ++j) {
      bv[KK][j] = biases[cb + j];
      cnt[KK][j] = 0u;
    }
    init_k<K0, FS, KK + 1>(biases, colbase, FTOT, jb, bv, cnt);
  }
}

template <int K0, int FS, int KK>
__device__ __forceinline__ void write_k(unsigned* __restrict__ outT, int colbase,
                                        int FTOT, int jb, int n,
                                        const unsigned (&cnt)[GK][FS]) {
  if constexpr (KK < GK) {
    const int cb = colbase + (K0 + KK) * FTOT + jb;
#pragma unroll
    for (int j = 0; j < FS; ++j) {
      atomicAdd(&outT[(cb + j) * NS + n], cnt[KK][j]);  // coalesced per wave
    }
    write_k<K0, FS, KK + 1>(outT, colbase, FTOT, jb, n, cnt);
  }
}

// One t-range segment. Unconditional loads from the padded array, single
// per-lane base xb, index (t + j*d)*NS. unroll 1: no live-range blowup.
template <int K0, int FS, int PSEL>
__device__ __forceinline__ void run_seg(int tlo, int thi, int d,
                                        const float* __restrict__ xb,
                                        const float (&bv)[GK][FS],
                                        unsigned (&cnt)[GK][FS]) {
#pragma unroll 1
  for (int t = tlo; t < thi; ++t) {
    float s[9];
#pragma unroll
    for (int j = 0; j < 9; ++j) s[j] = xb[(t + j * d) * NS];
    // sequential left-fold, matching reference reduce order (pad zeros included)
    float sum = s[0];
#pragma unroll
    for (int j = 1; j < 9; ++j) sum += s[j];
    do_kernels<K0, FS, PSEL, 0>(s, sum, bv, cnt);
  }
}

template <int K0, int FS>
__device__ __forceinline__ void body(const float* __restrict__ xTp,
                                     const float* __restrict__ biases,
                                     unsigned* __restrict__ outT, int d, int par,
                                     int FTOT, int jb, int colbase, int ts) {
  const int n = (int)threadIdx.x;  // sample id (4 waves x 64 lanes)
  // per-lane base: row (ROW0 - 4d), sample n. Tap j at row offset (t + j*d).
  const float* xb = xTp + (ROW0 - 4 * d) * NS + n;

  float bv[GK][FS];
  unsigned cnt[GK][FS];
  init_k<K0, FS, 0>(biases, colbase, FTOT, jb, bv, cnt);

  const int p = 4 * d;
  const int t0 = ts * TCH, t1 = t0 + TCH;
  // [0,p) and [L-p,L): padded-parity kernels only. [p,L-p): all kernels.
  const int aHi = imin(t1, p);
  const int bLo = imax(t0, p), bHi = imin(t1, LSER - p);
  const int cLo = imax(t0, LSER - p);

  if (par == 0) {
    run_seg<K0, FS, 0>(t0, aHi, d, xb, bv, cnt);
  } else {
    run_seg<K0, FS, 1>(t0, aHi, d, xb, bv, cnt);
  }
  run_seg<K0, FS, -1>(bLo, bHi, d, xb, bv, cnt);
  if (par == 0) {
    run_seg<K0, FS, 0>(cLo, t1, d, xb, bv, cnt);
  } else {
    run_seg<K0, FS, 1>(cLo, t1, d, xb, bv, cnt);
  }

  write_k<K0, FS, 0>(outT, colbase, FTOT, jb, n, cnt);
}

// dispatch over 14 kernel groups at compile-time K0 = G*6
template <int FS>
__device__ __forceinline__ void dispatch_g(int g, const float* __restrict__ xTp,
                                           const float* __restrict__ biases,
                                           unsigned* __restrict__ outT, int d, int par,
                                           int FTOT, int jb, int colbase, int ts) {
  switch (g) {
    case 0:  body<0,  FS>(xTp, biases, outT, d, par, FTOT, jb, colbase, ts); break;
    case 1:  body<6,  FS>(xTp, biases, outT, d, par, FTOT, jb, colbase, ts); break;
    case 2:  body<12, FS>(xTp, biases, outT, d, par, FTOT, jb, colbase, ts); break;
    case 3:  body<18, FS>(xTp, biases, outT, d, par, FTOT, jb, colbase, ts); break;
    case 4:  body<24, FS>(xTp, biases, outT, d, par, FTOT, jb, colbase, ts); break;
    case 5:  body<30, FS>(xTp, biases, outT, d, par, FTOT, jb, colbase, ts); break;
    case 6:  body<36, FS>(xTp, biases, outT, d, par, FTOT, jb, colbase, ts); break;
    case 7:  body<42, FS>(xTp, biases, outT, d, par, FTOT, jb, colbase, ts); break;
    case 8:  body<48, FS>(xTp, biases, outT, d, par, FTOT, jb, colbase, ts); break;
    case 9:  body<54, FS>(xTp, biases, outT, d, par, FTOT, jb, colbase, ts); break;
    case 10: body<60, FS>(xTp, biases, outT, d, par, FTOT, jb, colbase, ts); break;
    case 11: body<66, FS>(xTp, biases, outT, d, par, FTOT, jb, colbase, ts); break;
    case 12: body<72, FS>(xTp, biases, outT, d, par, FTOT, jb, colbase, ts); break;
    default: body<78, FS>(xTp, biases, outT, d, par, FTOT, jb, colbase, ts); break;
  }
}

}  // namespace

// ---------------------------------------------------------------------------

__global__ __launch_bounds__(256) void mr_transpose(const float* __restrict__ x,
                                                    float* __restrict__ xTp) {
  __shared__ float tile[32][33];
  const int t0 = blockIdx.x << 5;
  const int n0 = blockIdx.y << 5;
  const int tx = threadIdx.x & 31, ty = threadIdx.x >> 5;  // 32 x 8
#pragma unroll
  for (int i = 0; i < 32; i += 8)
    tile[ty + i][tx] = x[(n0 + ty + i) * LSER + t0 + tx];
  __syncthreads();
#pragma unroll
  for (int i = 0; i < 32; i += 8)
    xTp[(ROW0 + t0 + ty + i) * NS + n0 + tx] = tile[tx][ty + i];
}

__global__ __launch_bounds__(256) void mr_main(const float* __restrict__ xTp,
                                               const float* __restrict__ biases,
                                               unsigned* __restrict__ outT) {
  const int bid = (int)blockIdx.x;  // ALL selectors blockIdx-only (wave-uniform)
  int di = 0;
#pragma unroll 1
  while (di < NDIL - 1 && bid >= c_BSTART[di + 1]) ++di;
  const int rel = bid - c_BSTART[di];
  const int split = rel / 224;          // 4-wide bias split (14 groups x 16 ts)
  const int r2 = rel - split * 224;
  const int g = r2 >> 4;                // kernel group 0..13
  const int ts = r2 & 15;               // t-slice 0..15
  const int d = c_DIL[di];
  const int FTOT = c_F[di];
  const int colbase = c_FOFF[di];
  const int par = di & 1;
  const int jb = split << 2;
  const int FS = imin(4, FTOT - jb);

  if (FS == 4) {
    dispatch_g<4>(g, xTp, biases, outT, d, par, FTOT, jb, colbase, ts);
  } else {  // FS == 3
    dispatch_g<3>(g, xTp, biases, outT, d, par, FTOT, jb, colbase, ts);
  }
}

__global__ __launch_bounds__(256) void mr_finalize(const unsigned* __restrict__ outT,
                                                   float* __restrict__ out) {
  __shared__ unsigned tile[64][65];
  __shared__ float sscale[64];
  const int tb = (int)blockIdx.x;  // 628 = 157 col-tiles x 4 n-tiles
  const int ct = tb % 157, nt = tb / 157;
  const int c0 = ct << 6, n0 = nt << 6;
  const int tid = (int)threadIdx.x;

  if (tid < 64) {
    const int col = c0 + tid;
    float sc = 0.0f;
    if (col < NFEAT) {
      int di = 0;
      while (di < NDIL - 1 && col >= c_FOFF[di + 1]) ++di;
      const int rel = col - c_FOFF[di];
      const int f = c_F[di];
      const int k = rel / f;
      const int d = c_DIL[di];
      const bool padded = (((di + k) & 1) == 0);
      const int T = padded ? LSER : (LSER - 8 * d);
      sc = 1.0f / (float)T;
    }
    sscale[tid] = sc;
  }
#pragma unroll
  for (int i = 0; i < 16; ++i) {
    const int lin = tid + (i << 8);
    const int dc = lin >> 6, dn = lin & 63;
    const int col = c0 + dc;
    tile[dc][dn] = (col < NFEAT) ? outT[col * NS + n0 + dn] : 0u;
  }
  __syncthreads();
#pragma unroll
  for (int i = 0; i < 16; ++i) {
    const int lin = tid + (i << 8);
    const int dn = lin >> 6, dc = lin & 63;
    const int col = c0 + dc;
    if (col < NFEAT)
      out[(n0 + dn) * NFEAT + col] = (float)tile[dc][dn] * sscale[dc];
  }
}

extern "C" void kernel_launch(void* const* d_in, const int* in_sizes, int n_in,
                              void* d_out, int out_size, void* d_ws, size_t ws_size,
                              hipStream_t stream) {
  (void)in_sizes; (void)n_in; (void)out_size; (void)ws_size;
  const float* x = (const float*)d_in[0];        // (256, 1, 1024) f32
  const float* biases = (const float*)d_in[1];   // (9996,) f32
  float* out = (float*)d_out;                    // (256, 9996) f32

  float* xTp = (float*)d_ws;                                   // 2 MiB (2048x256 f32)
  unsigned* outT = (unsigned*)((char*)d_ws + (size_t)(PADROWS * NS * 4));

  // zero pad rows + counters in one memset (regions are contiguous)
  hipMemsetAsync(d_ws, 0,
                 (size_t)PADROWS * NS * 4 + (size_t)NFEAT * NS * sizeof(unsigned),
                 stream);
  hipLaunchKernelGGL(mr_transpose, dim3(32, 8), dim3(256), 0, stream, x, xTp);
  hipLaunchKernelGGL(mr_main, dim3(NBLK), dim3(256), 0, stream, xTp, biases, outT);
  hipLaunchKernelGGL(mr_finalize, dim3(628), dim3(256), 0, stream, outT, out);
}